// Round 1
// 60.027 us; speedup vs baseline: 1.0016x; 1.0016x over previous
//
#include <hip/hip_runtime.h>
#include <math.h>

#define N 4096
#define M 4095          // number of segments
#define EPSF 1e-9f
#define NT 1024         // single block, 16 waves, 1 CU, 1 graph node
#define INV_4PI 0.07957747154594767f

// Algebra (verified R1/R2, absmax 0.0 in the prior session):
//  (1) q_bio = normalize(eye(4)[idx]) is an EXACT one-hot in fp32
//      (1.0f + 1e-9f == 1.0f), so (dr2_j, m2_j) depends only on the type
//      t=(idx[j], idx[j+1]) -- 16 compile-time constants; O(M^2) -> O(M*6).
//  (2) Swapping (a,b)->(b,a) flips dr2 but keeps m2, so the term is
//      antisymmetric: 12 types fold to 6 with signed weights
//      w_ab = cnt[a,b] - cnt[b,a].
//  (3) NEW this round: sum_i sum_t w[t]*f_t(i) == sum_t w[t] * (sum_i f_t(i)).
//      The weights factor out of the double sum, so per-thread partials S[t]
//      are independent of the histogram -> the histogram needs NO atomics
//      (per-thread register counters W[t]) and phase1/phase2 fuse into one
//      pass with zero mid-kernel barriers and zero LDS staging.
//  (4) theta = b/255 * 2pi, and v_sin_f32/v_cos_f32 take REVOLUTIONS:
//      sin(theta) = v_sin(b/255), b/255 in [0,1) -- no range reduction.
__global__ __launch_bounds__(NT) void fused_gauss_kernel(
    const float* __restrict__ bytes, const int* __restrict__ idx,
    float* __restrict__ out) {
  __shared__ float red[NT / 64][12];   // 16 waves x (6 S + 6 W)
  __shared__ float fin[12];

  const int t = threadIdx.x;

  // ---- coalesced vector loads: thread t owns points 4t..4t+3 (+ neighbor) ----
  const float4 b4 = reinterpret_cast<const float4*>(bytes)[t];
  const int4 i4 = reinterpret_cast<const int4*>(idx)[t];
  const bool last = (t == NT - 1);
  const float b5 = last ? 0.0f : bytes[4 * t + 4];   // guard OOB at point 4096
  const int i5 = last ? 0 : idx[4 * t + 4];

  const float bb[5] = {b4.x, b4.y, b4.z, b4.w, b5};
  const int ii[5] = {i4.x, i4.y, i4.z, i4.w, i5};

  // ---- 5 normalized r1 points, all in registers (no LDS) ----
  float px[5], py[5], pz[5];
#pragma unroll
  for (int k = 0; k < 5; ++k) {
    float rev = bb[k] * (1.0f / 255.0f);             // revolutions in [0,1)
    float s = __builtin_amdgcn_sinf(rev);            // v_sin_f32: sin(2*pi*rev)
    float c = __builtin_amdgcn_cosf(rev);            // v_cos_f32
    float q1 = 0.5f * s, q2 = 0.3f * s, q3 = 0.2f * s;
    float n2 = c * c + q1 * q1 + q2 * q2 + q3 * q3 + EPSF;
    float inv = rsqrtf(n2);
    inv = inv * (1.5f - 0.5f * n2 * inv * inv);      // Newton -> ~1 ulp
    px[k] = q1 * inv;
    py[k] = q2 * inv;
    pz[k] = q3 * inv;
  }

  // 6 unordered types (a<b): dr2 = P[b]-P[a], m2 = (P[a]+P[b])/2, const-folded.
  const float EX[6] = {1.f, 0.f, 0.f, -1.f, -1.f, 0.f};
  const float EY[6] = {0.f, 1.f, 0.f, 1.f, 0.f, -1.f};
  const float EZ[6] = {0.f, 0.f, 1.f, 0.f, 1.f, 1.f};
  const float M2X[6] = {0.5f, 0.f, 0.f, 0.5f, 0.5f, 0.f};
  const float M2Y[6] = {0.f, 0.5f, 0.f, 0.5f, 0.f, 0.5f};
  const float M2Z[6] = {0.f, 0.f, 0.5f, 0.f, 0.5f, 0.5f};
  const int AB[6] = {0 * 4 + 1, 0 * 4 + 2, 0 * 4 + 3, 1 * 4 + 2, 1 * 4 + 3, 2 * 4 + 3};
  const int BA[6] = {1 * 4 + 0, 2 * 4 + 0, 3 * 4 + 0, 2 * 4 + 1, 3 * 4 + 1, 3 * 4 + 2};

  float S[6] = {0.f, 0.f, 0.f, 0.f, 0.f, 0.f};   // unweighted geometric partials
  float W[6] = {0.f, 0.f, 0.f, 0.f, 0.f, 0.f};   // signed type counts (exact in f32)

#pragma unroll
  for (int k = 0; k < 4; ++k) {
    if (4 * t + k < M) {   // only k==3 on the last thread fails (seg 4095)
      float ax = px[k], ay = py[k], az = pz[k];
      float bx = px[k + 1], by = py[k + 1], bz = pz[k + 1];
      float d1x = bx - ax, d1y = by - ay, d1z = bz - az;
      float m1x = 0.5f * (bx + ax), m1y = 0.5f * (by + ay), m1z = 0.5f * (bz + az);
      int u = ii[k] * 4 + ii[k + 1];

#pragma unroll
      for (int q = 0; q < 6; ++q) {
        float dx = m1x - M2X[q], dy = m1y - M2Y[q], dz = m1z - M2Z[q];
        float cx = d1y * EZ[q] - d1z * EY[q];     // cross(d1, e), e in {0,+-1}
        float cy = d1z * EX[q] - d1x * EZ[q];     // -> const-folds to adds
        float cz = d1x * EY[q] - d1y * EX[q];
        float num = cx * dx + cy * dy + cz * dz;
        float d2 = dx * dx + dy * dy + dz * dz + EPSF;
        float inv = rsqrtf(d2);
        inv = inv * (1.5f - 0.5f * d2 * inv * inv);   // Newton -> ~1 ulp
        S[q] += num * (inv * inv * inv);
        W[q] += (u == AB[q] ? 1.0f : 0.0f) - (u == BA[q] ? 1.0f : 0.0f);
      }
    }
  }

  // ---- reduce 12 values across each 64-lane wave ----
#pragma unroll
  for (int off = 32; off > 0; off >>= 1) {
#pragma unroll
    for (int q = 0; q < 6; ++q) {
      S[q] += __shfl_down(S[q], off, 64);
      W[q] += __shfl_down(W[q], off, 64);
    }
  }
  const int lane = t & 63, wid = t >> 6;
  if (lane == 0) {
#pragma unroll
    for (int q = 0; q < 6; ++q) {
      red[wid][q] = S[q];
      red[wid][q + 6] = W[q];
    }
  }
  __syncthreads();

  // ---- cross-wave: 12 threads each sum the 16 wave partials ----
  if (t < 12) {
    float v = 0.0f;
#pragma unroll
    for (int w = 0; w < NT / 64; ++w) v += red[w][t];
    fin[t] = v;
  }
  __syncthreads();
  if (t == 0) {
    float r = 0.0f;
#pragma unroll
    for (int q = 0; q < 6; ++q) r += fin[q + 6] * fin[q];   // sum_t w[t] * S[t]
    out[0] = r * INV_4PI;
  }
}

extern "C" void kernel_launch(void* const* d_in, const int* in_sizes, int n_in,
                              void* d_out, int out_size, void* d_ws, size_t ws_size,
                              hipStream_t stream) {
  const float* bytes = (const float*)d_in[0];
  const int* idx = (const int*)d_in[1];
  float* out = (float*)d_out;

  fused_gauss_kernel<<<dim3(1), dim3(NT), 0, stream>>>(bytes, idx, out);
}

// Round 2
// 58.095 us; speedup vs baseline: 1.0349x; 1.0333x over previous
//
#include <hip/hip_runtime.h>
#include <math.h>

#define N 4096
#define M 4095          // number of segments
#define EPSF 1e-9f
#define NB 64           // phase-1 blocks: 64 blocks x 64 threads = 1 wave/block
#define INV_4PI 0.07957747154594767f

// Algebra (verified absmax 0.0 in rounds 0-1):
//  (1) q_bio = normalize(eye(4)[idx]) is an EXACT one-hot in fp32
//      (1.0f + 1e-9f == 1.0f), so (dr2_j, m2_j) depends only on the type
//      t=(idx[j], idx[j+1]) -- compile-time constants; O(M^2) -> O(M*6).
//  (2) Swapping (a,b)->(b,a) flips dr2 but keeps m2: antisymmetric, 12
//      ordered types fold to 6 with signed weights w_ab = cnt[a,b]-cnt[b,a].
//  (3) sum_i sum_t w[t]*f_t(i) == sum_t w[t]*(sum_i f_t(i)): weights factor
//      out of the double sum -> no histogram needed before the sweep; W and
//      S accumulate independently and multiply once at the very end.
//  (4) theta = b/255 * 2pi and v_sin_f32/v_cos_f32 take REVOLUTIONS:
//      sin(theta) = v_sin(b/255), b/255 in [0,1) -- no range reduction.
//  (5) NEW this round: the single 1024-thread block serialized ~950 VALU
//      ops/thread on ONE CU (~4.5 us). Split across 64 CUs (1 wave each,
//      1 segment/thread) + a 1-wave finisher node reading d_ws. Kernel
//      boundary guarantees visibility of phase-1 stores (no fences needed);
//      plain stores to d_ws avoid any poisoned-workspace init problem.

__device__ __forceinline__ void norm_point(float b, float& x, float& y, float& z) {
  float rev = b * (1.0f / 255.0f);               // revolutions in [0,1)
  float s = __builtin_amdgcn_sinf(rev);          // v_sin_f32: sin(2*pi*rev)
  float c = __builtin_amdgcn_cosf(rev);          // v_cos_f32
  float q1 = 0.5f * s, q2 = 0.3f * s, q3 = 0.2f * s;
  float n2 = c * c + q1 * q1 + q2 * q2 + q3 * q3 + EPSF;
  float inv = rsqrtf(n2);
  inv = inv * (1.5f - 0.5f * n2 * inv * inv);    // Newton -> ~1 ulp
  x = q1 * inv; y = q2 * inv; z = q3 * inv;
}

// Phase 1: one segment per thread, 64 blocks x 64 threads. Wave-reduce the
// 12 partials, lane 0 stores them type-major into ws[q*NB + blockIdx.x].
__global__ __launch_bounds__(64) void gauss_part1(
    const float* __restrict__ bytes, const int* __restrict__ idx,
    float* __restrict__ ws) {
  const int s = blockIdx.x * 64 + threadIdx.x;   // segment id

  // 6 unordered types (a<b): dr2 = P[b]-P[a], m2 = (P[a]+P[b])/2, const-folded.
  const float EX[6] = {1.f, 0.f, 0.f, -1.f, -1.f, 0.f};
  const float EY[6] = {0.f, 1.f, 0.f, 1.f, 0.f, -1.f};
  const float EZ[6] = {0.f, 0.f, 1.f, 0.f, 1.f, 1.f};
  const float M2X[6] = {0.5f, 0.f, 0.f, 0.5f, 0.5f, 0.f};
  const float M2Y[6] = {0.f, 0.5f, 0.f, 0.5f, 0.f, 0.5f};
  const float M2Z[6] = {0.f, 0.f, 0.5f, 0.f, 0.5f, 0.5f};
  const int AB[6] = {0 * 4 + 1, 0 * 4 + 2, 0 * 4 + 3, 1 * 4 + 2, 1 * 4 + 3, 2 * 4 + 3};
  const int BA[6] = {1 * 4 + 0, 2 * 4 + 0, 3 * 4 + 0, 2 * 4 + 1, 3 * 4 + 1, 3 * 4 + 2};

  float S[6] = {0.f, 0.f, 0.f, 0.f, 0.f, 0.f};
  float W[6] = {0.f, 0.f, 0.f, 0.f, 0.f, 0.f};

  if (s < M) {
    float ax, ay, az, bx, by, bz;
    norm_point(bytes[s], ax, ay, az);
    norm_point(bytes[s + 1], bx, by, bz);
    const int u = idx[s] * 4 + idx[s + 1];

    const float d1x = bx - ax, d1y = by - ay, d1z = bz - az;
    const float m1x = 0.5f * (bx + ax), m1y = 0.5f * (by + ay), m1z = 0.5f * (bz + az);

#pragma unroll
    for (int q = 0; q < 6; ++q) {
      float dx = m1x - M2X[q], dy = m1y - M2Y[q], dz = m1z - M2Z[q];
      float cx = d1y * EZ[q] - d1z * EY[q];      // cross(d1, e), e in {0,+-1}
      float cy = d1z * EX[q] - d1x * EZ[q];      // -> const-folds to adds
      float cz = d1x * EY[q] - d1y * EX[q];
      float num = cx * dx + cy * dy + cz * dz;
      float d2 = dx * dx + dy * dy + dz * dz + EPSF;
      float inv = rsqrtf(d2);
      inv = inv * (1.5f - 0.5f * d2 * inv * inv);   // Newton -> ~1 ulp
      S[q] = num * (inv * inv * inv);
      W[q] = (u == AB[q] ? 1.0f : 0.0f) - (u == BA[q] ? 1.0f : 0.0f);
    }
  }

  // 64-lane wave reduction of the 12 partials (no LDS, no barrier).
#pragma unroll
  for (int off = 32; off > 0; off >>= 1) {
#pragma unroll
    for (int q = 0; q < 6; ++q) {
      S[q] += __shfl_down(S[q], off, 64);
      W[q] += __shfl_down(W[q], off, 64);
    }
  }
  if (threadIdx.x == 0) {
#pragma unroll
    for (int q = 0; q < 6; ++q) {
      ws[q * NB + blockIdx.x] = S[q];            // type-major for phase 2
      ws[(6 + q) * NB + blockIdx.x] = W[q];
    }
  }
}

// Phase 2: one wave. Lane l holds block-l's 12 partials; 12 wave reductions,
// then lane 0 forms sum_t W[t]*S[t] and stores the scalar.
__global__ __launch_bounds__(64) void gauss_part2(
    const float* __restrict__ ws, float* __restrict__ out) {
  const int l = threadIdx.x;
  float v[12];
#pragma unroll
  for (int q = 0; q < 12; ++q) v[q] = ws[q * NB + l];
#pragma unroll
  for (int off = 32; off > 0; off >>= 1) {
#pragma unroll
    for (int q = 0; q < 12; ++q) v[q] += __shfl_down(v[q], off, 64);
  }
  if (l == 0) {
    float r = 0.0f;
#pragma unroll
    for (int q = 0; q < 6; ++q) r += v[6 + q] * v[q];   // sum_t w[t]*S[t]
    out[0] = r * INV_4PI;
  }
}

extern "C" void kernel_launch(void* const* d_in, const int* in_sizes, int n_in,
                              void* d_out, int out_size, void* d_ws, size_t ws_size,
                              hipStream_t stream) {
  const float* bytes = (const float*)d_in[0];
  const int* idx = (const int*)d_in[1];
  float* out = (float*)d_out;
  float* ws = (float*)d_ws;

  gauss_part1<<<dim3(NB), dim3(64), 0, stream>>>(bytes, idx, ws);
  gauss_part2<<<dim3(1), dim3(64), 0, stream>>>(ws, out);
}